// Round 1
// baseline (877.798 us; speedup 1.0000x reference)
//
#include <hip/hip_runtime.h>
#include <hip/hip_bf16.h>

// ---------------------------------------------------------------------------
// Types / helpers
// ---------------------------------------------------------------------------
typedef __bf16 bf16x8 __attribute__((ext_vector_type(8)));
typedef float f32x4 __attribute__((ext_vector_type(4)));
typedef unsigned short ushort8 __attribute__((ext_vector_type(8)));

// fp32 -> bf16 bits, round-to-nearest-even (inputs are finite; no NaN path)
__device__ __forceinline__ unsigned short f2bs(float f) {
    unsigned u = __builtin_bit_cast(unsigned, f);
    u = (u + 0x7fffu + ((u >> 16) & 1u)) >> 16;
    return (unsigned short)u;
}
__device__ __forceinline__ float bs2f(unsigned short s) {
    unsigned u = ((unsigned)s) << 16;
    return __builtin_bit_cast(float, u);
}

#define GLDS16(gp, lp)                                                        \
    __builtin_amdgcn_global_load_lds(                                         \
        (const __attribute__((address_space(1))) void*)(gp),                  \
        (__attribute__((address_space(3))) void*)(lp), 16, 0, 0)

// ---------------------------------------------------------------------------
// Kernel 1: feats — X[m, 0:768) = exclusive prefix mean, X[m, 768:1536) = h
// grid (B, D/256), block 256. fp32 running sum for accuracy.
// ---------------------------------------------------------------------------
__global__ __launch_bounds__(256) void feats_kernel(
    const float* __restrict__ h, unsigned short* __restrict__ X,
    int B, int T, int D) {
    const int d = blockIdx.y * blockDim.x + threadIdx.x;  // < D
    const int b = blockIdx.x;
    const float* hp = h + ((long)b * T) * D + d;
    unsigned short* xp = X + ((long)b * T) * (2 * D) + d;
    float sum = 0.f;
    for (int t = 0; t < T; ++t) {
        float pm = (t == 0) ? 0.f : sum / (float)t;
        float v = hp[0];
        xp[0] = f2bs(pm);
        xp[D] = f2bs(v);
        sum += v;
        hp += D;
        xp += 2 * D;
    }
}

// ---------------------------------------------------------------------------
// Kernel 2: transpose + cast. W: [K][N] fp32 -> WT: [N][K] bf16 bits.
// grid (N/32, K/32), block (32, 8)
// ---------------------------------------------------------------------------
__global__ __launch_bounds__(256) void transpose_cast(
    const float* __restrict__ W, unsigned short* __restrict__ WT,
    int K, int N) {
    __shared__ float tile[32][33];
    const int n0 = blockIdx.x * 32, k0 = blockIdx.y * 32;
    const int tx = threadIdx.x, ty = threadIdx.y;
    #pragma unroll
    for (int i = ty; i < 32; i += 8)
        tile[i][tx] = W[(long)(k0 + i) * N + n0 + tx];
    __syncthreads();
    #pragma unroll
    for (int i = ty; i < 32; i += 8)
        WT[(long)(n0 + i) * K + k0 + tx] = f2bs(tile[tx][i]);
}

// ---------------------------------------------------------------------------
// Kernel 3: GEMM  C[M,N] = act(A[M,K] * BT[N,K]^T + bias)
// m97-verified structure: 128x128 tile, BK=32, 4 waves 2x2, 16x16x32 bf16
// MFMA, global_load_lds width 16. All dims exact multiples (no edge code).
// ---------------------------------------------------------------------------
__global__ __launch_bounds__(256) void gemm_bt_bias_act(
    const unsigned short* __restrict__ A,   // [M,K] bf16 bits
    const unsigned short* __restrict__ BT,  // [N,K] bf16 bits
    const float* __restrict__ bias,         // [N]
    unsigned short* __restrict__ C,         // [M,N] bf16 bits
    int M, int N, int K, int do_relu) {
    __shared__ __align__(16) unsigned short As[128 * 32];
    __shared__ __align__(16) unsigned short Bs[128 * 32];

    const int tid = threadIdx.x;
    const int lane = tid & 63;
    const int wave = tid >> 6;
    const int wm = (wave >> 1) * 64;
    const int wn = (wave & 1) * 64;
    const int lane16 = lane & 15;
    const int quad = lane >> 4;

    const long row0 = (long)blockIdx.x * 128;
    const long col0 = (long)blockIdx.y * 128;

    const unsigned short* Ab = A + row0 * K;
    const unsigned short* Bb = BT + col0 * K;

    const int sr = tid >> 2;         // staging row 0..63
    const int sc = (tid & 3) * 8;    // staging col (elements)

    f32x4 acc[4][4];
    #pragma unroll
    for (int i = 0; i < 4; ++i)
        #pragma unroll
        for (int j = 0; j < 4; ++j)
            acc[i][j] = (f32x4){0.f, 0.f, 0.f, 0.f};

    for (int kt = 0; kt < K; kt += 32) {
        // stage 128x32 A-tile and 128x32 BT-tile, 16 B/lane direct-to-LDS
        GLDS16(Ab + (long)sr * K + kt + sc,        As + tid * 8);
        GLDS16(Ab + (long)(sr + 64) * K + kt + sc, As + (256 + tid) * 8);
        GLDS16(Bb + (long)sr * K + kt + sc,        Bs + tid * 8);
        GLDS16(Bb + (long)(sr + 64) * K + kt + sc, Bs + (256 + tid) * 8);
        __syncthreads();

        bf16x8 af[4], bfr[4];
        #pragma unroll
        for (int i = 0; i < 4; ++i)
            af[i] = *(const bf16x8*)(As + (wm + i * 16 + lane16) * 32 + quad * 8);
        #pragma unroll
        for (int j = 0; j < 4; ++j)
            bfr[j] = *(const bf16x8*)(Bs + (wn + j * 16 + lane16) * 32 + quad * 8);

        #pragma unroll
        for (int i = 0; i < 4; ++i)
            #pragma unroll
            for (int j = 0; j < 4; ++j)
                acc[i][j] = __builtin_amdgcn_mfma_f32_16x16x32_bf16(
                    af[i], bfr[j], acc[i][j], 0, 0, 0);

        __syncthreads();
    }

    // Epilogue: C/D layout col=lane&15, row=quad*4+reg  (m89/m91 verified)
    #pragma unroll
    for (int i = 0; i < 4; ++i) {
        #pragma unroll
        for (int r = 0; r < 4; ++r) {
            const long row = row0 + wm + i * 16 + quad * 4 + r;
            #pragma unroll
            for (int j = 0; j < 4; ++j) {
                const long col = col0 + wn + j * 16 + lane16;
                float v = acc[i][j][r] + bias[col];
                if (do_relu) v = fmaxf(v, 0.f);
                C[row * N + col] = f2bs(v);
            }
        }
    }
}

// ---------------------------------------------------------------------------
// Kernel 4: head — out[m] = dot(H2[m,:1024], W3) + b3. One wave per row.
// grid (M/4), block 256 (4 waves).
// ---------------------------------------------------------------------------
__global__ __launch_bounds__(256) void head_kernel(
    const unsigned short* __restrict__ H2, const float* __restrict__ W3,
    const float* __restrict__ b3, float* __restrict__ out, int M) {
    const int lane = threadIdx.x & 63;
    const int wave = threadIdx.x >> 6;
    const long row = (long)blockIdx.x * 4 + wave;
    const unsigned short* p = H2 + row * 1024 + lane * 16;
    ushort8 v0 = *(const ushort8*)p;
    ushort8 v1 = *(const ushort8*)(p + 8);
    const float* w = W3 + lane * 16;
    float s = 0.f;
    #pragma unroll
    for (int u = 0; u < 8; ++u) s += bs2f(v0[u]) * w[u];
    #pragma unroll
    for (int u = 0; u < 8; ++u) s += bs2f(v1[u]) * w[8 + u];
    #pragma unroll
    for (int off = 32; off > 0; off >>= 1) s += __shfl_down(s, off, 64);
    if (lane == 0) out[row] = s + b3[0];
}

// ---------------------------------------------------------------------------
// Launch
// ---------------------------------------------------------------------------
extern "C" void kernel_launch(void* const* d_in, const int* in_sizes, int n_in,
                              void* d_out, int out_size, void* d_ws,
                              size_t ws_size, hipStream_t stream) {
    const float* h  = (const float*)d_in[0];
    const float* W1 = (const float*)d_in[1];
    const float* b1 = (const float*)d_in[2];
    const float* W2 = (const float*)d_in[3];
    const float* b2 = (const float*)d_in[4];
    const float* W3 = (const float*)d_in[5];
    const float* b3 = (const float*)d_in[6];
    float* out = (float*)d_out;

    const int B = 128, T = 254, D = 768, H = 1024;
    const int M = B * T;        // 32512 = 254 * 128
    const int K1 = 2 * D;       // 1536
    const int N1 = 2 * H;       // 2048
    const int K2 = N1;          // 2048
    const int N2 = H;           // 1024

    char* ws = (char*)d_ws;
    size_t off = 0;
    auto alloc = [&](size_t bytes) {
        char* p = ws + off;
        off += (bytes + 255) & ~(size_t)255;
        return p;
    };
    unsigned short* X   = (unsigned short*)alloc((size_t)M * K1 * 2);  // 99.9 MB
    unsigned short* H1  = (unsigned short*)alloc((size_t)M * N1 * 2);  // 133.2 MB
    unsigned short* W1T = (unsigned short*)alloc((size_t)N1 * K1 * 2); // 6.3 MB
    unsigned short* W2T = (unsigned short*)alloc((size_t)N2 * K2 * 2); // 4.2 MB
    // H2 reuses X's region (X dead after GEMM1; 66.6 MB <= 99.9 MB)
    unsigned short* H2 = X;

    dim3 tb(32, 8);
    transpose_cast<<<dim3(N1 / 32, K1 / 32), tb, 0, stream>>>(W1, W1T, K1, N1);
    transpose_cast<<<dim3(N2 / 32, K2 / 32), tb, 0, stream>>>(W2, W2T, K2, N2);

    feats_kernel<<<dim3(B, D / 256), 256, 0, stream>>>(h, X, B, T, D);

    gemm_bt_bias_act<<<dim3(M / 128, N1 / 128), 256, 0, stream>>>(
        X, W1T, b1, H1, M, N1, K1, 1);
    gemm_bt_bias_act<<<dim3(M / 128, N2 / 128), 256, 0, stream>>>(
        H1, W2T, b2, H2, M, N2, K2, 1);

    head_kernel<<<dim3(M / 4), 256, 0, stream>>>(H2, W3, b3, out, M);
}

// Round 2
// 750.675 us; speedup vs baseline: 1.1693x; 1.1693x over previous
//
#include <hip/hip_runtime.h>
#include <hip/hip_bf16.h>

// ---------------------------------------------------------------------------
// Types / helpers
// ---------------------------------------------------------------------------
typedef __bf16 bf16x8 __attribute__((ext_vector_type(8)));
typedef float f32x4 __attribute__((ext_vector_type(4)));
typedef unsigned short ushort8 __attribute__((ext_vector_type(8)));

// fp32 -> bf16 bits, round-to-nearest-even (inputs are finite; no NaN path)
__device__ __forceinline__ unsigned short f2bs(float f) {
    unsigned u = __builtin_bit_cast(unsigned, f);
    u = (u + 0x7fffu + ((u >> 16) & 1u)) >> 16;
    return (unsigned short)u;
}
__device__ __forceinline__ float bs2f(unsigned short s) {
    unsigned u = ((unsigned)s) << 16;
    return __builtin_bit_cast(float, u);
}

#define GLDS16(gp, lp)                                                        \
    __builtin_amdgcn_global_load_lds(                                         \
        (const __attribute__((address_space(1))) void*)(gp),                  \
        (__attribute__((address_space(3))) void*)(lp), 16, 0, 0)

// ---------------------------------------------------------------------------
// Kernel 1: feats — X[m, 0:768) = exclusive prefix mean, X[m, 768:1536) = h
// grid (B, D/256), block 256. fp32 running sum for accuracy.
// ---------------------------------------------------------------------------
__global__ __launch_bounds__(256) void feats_kernel(
    const float* __restrict__ h, unsigned short* __restrict__ X,
    int B, int T, int D) {
    const int d = blockIdx.y * blockDim.x + threadIdx.x;  // < D
    const int b = blockIdx.x;
    const float* hp = h + ((long)b * T) * D + d;
    unsigned short* xp = X + ((long)b * T) * (2 * D) + d;
    float sum = 0.f;
    for (int t = 0; t < T; ++t) {
        float pm = (t == 0) ? 0.f : sum / (float)t;
        float v = hp[0];
        xp[0] = f2bs(pm);
        xp[D] = f2bs(v);
        sum += v;
        hp += D;
        xp += 2 * D;
    }
}

// ---------------------------------------------------------------------------
// Kernel 2: transpose + cast. W: [K][N] fp32 -> WT: [N][K] bf16 bits.
// grid (N/32, K/32), block (32, 8)
// ---------------------------------------------------------------------------
__global__ __launch_bounds__(256) void transpose_cast(
    const float* __restrict__ W, unsigned short* __restrict__ WT,
    int K, int N) {
    __shared__ float tile[32][33];
    const int n0 = blockIdx.x * 32, k0 = blockIdx.y * 32;
    const int tx = threadIdx.x, ty = threadIdx.y;
    #pragma unroll
    for (int i = ty; i < 32; i += 8)
        tile[i][tx] = W[(long)(k0 + i) * N + n0 + tx];
    __syncthreads();
    #pragma unroll
    for (int i = ty; i < 32; i += 8)
        WT[(long)(n0 + i) * K + k0 + tx] = f2bs(tile[tx][i]);
}

// ---------------------------------------------------------------------------
// Kernel 2b: out[m] = b3 (init for the fused-head atomics)
// ---------------------------------------------------------------------------
__global__ __launch_bounds__(256) void init_out(
    float* __restrict__ out, const float* __restrict__ b3, int M) {
    int m = blockIdx.x * 256 + threadIdx.x;
    if (m < M) out[m] = b3[0];
}

// ---------------------------------------------------------------------------
// Kernel 3: GEMM  C[M,N] = relu(A[M,K] * BT[N,K]^T + bias)
// m97 structure: 128x128 tile, BK=32, 4 waves 2x2, 16x16x32 bf16 MFMA,
// global_load_lds width 16. grid (N/128, M/128): fast blockIdx.x walks the
// column blocks of ONE A row-panel -> concurrent A working set ~11 MB,
// B fully cache-resident -> A and B fetched from HBM ~once.
// FUSE: instead of storing C, accumulate out[row] += sum_col relu(v)*W3[col]
// (head layer), via lane16 shuffle-reduce + one atomicAdd per row-slot.
// ---------------------------------------------------------------------------
template <bool FUSE>
__global__ __launch_bounds__(256) void gemm_bt_bias_relu(
    const unsigned short* __restrict__ A,   // [M,K] bf16 bits
    const unsigned short* __restrict__ BT,  // [N,K] bf16 bits
    const float* __restrict__ bias,         // [N]
    unsigned short* __restrict__ C,         // [M,N] bf16 bits (unused if FUSE)
    const float* __restrict__ W3,           // [N] head weights (FUSE only)
    float* __restrict__ outp,               // [M] (FUSE only)
    int M, int N, int K) {
    __shared__ __align__(16) unsigned short As[128 * 32];
    __shared__ __align__(16) unsigned short Bs[128 * 32];

    const int tid = threadIdx.x;
    const int lane = tid & 63;
    const int wave = tid >> 6;
    const int wm = (wave >> 1) * 64;
    const int wn = (wave & 1) * 64;
    const int lane16 = lane & 15;
    const int quad = lane >> 4;

    const long row0 = (long)blockIdx.y * 128;
    const long col0 = (long)blockIdx.x * 128;

    const unsigned short* Ab = A + row0 * K;
    const unsigned short* Bb = BT + col0 * K;

    const int sr = tid >> 2;         // staging row 0..63
    const int sc = (tid & 3) * 8;    // staging col (elements)

    f32x4 acc[4][4];
    #pragma unroll
    for (int i = 0; i < 4; ++i)
        #pragma unroll
        for (int j = 0; j < 4; ++j)
            acc[i][j] = (f32x4){0.f, 0.f, 0.f, 0.f};

    for (int kt = 0; kt < K; kt += 32) {
        GLDS16(Ab + (long)sr * K + kt + sc,        As + tid * 8);
        GLDS16(Ab + (long)(sr + 64) * K + kt + sc, As + (256 + tid) * 8);
        GLDS16(Bb + (long)sr * K + kt + sc,        Bs + tid * 8);
        GLDS16(Bb + (long)(sr + 64) * K + kt + sc, Bs + (256 + tid) * 8);
        __syncthreads();

        bf16x8 af[4], bfr[4];
        #pragma unroll
        for (int i = 0; i < 4; ++i)
            af[i] = *(const bf16x8*)(As + (wm + i * 16 + lane16) * 32 + quad * 8);
        #pragma unroll
        for (int j = 0; j < 4; ++j)
            bfr[j] = *(const bf16x8*)(Bs + (wn + j * 16 + lane16) * 32 + quad * 8);

        #pragma unroll
        for (int i = 0; i < 4; ++i)
            #pragma unroll
            for (int j = 0; j < 4; ++j)
                acc[i][j] = __builtin_amdgcn_mfma_f32_16x16x32_bf16(
                    af[i], bfr[j], acc[i][j], 0, 0, 0);

        __syncthreads();
    }

    // Epilogue: C/D layout col=lane&15, row=quad*4+reg  (m89/m91 verified)
    if (!FUSE) {
        #pragma unroll
        for (int i = 0; i < 4; ++i) {
            #pragma unroll
            for (int r = 0; r < 4; ++r) {
                const long row = row0 + wm + i * 16 + quad * 4 + r;
                #pragma unroll
                for (int j = 0; j < 4; ++j) {
                    const long col = col0 + wn + j * 16 + lane16;
                    float v = acc[i][j][r] + bias[col];
                    v = fmaxf(v, 0.f);
                    C[row * N + col] = f2bs(v);
                }
            }
        }
    } else {
        // head fusion: part[i][r] = sum over this lane's 4 cols of relu(v)*W3
        float w3v[4], bv[4];
        #pragma unroll
        for (int j = 0; j < 4; ++j) {
            const long col = col0 + wn + j * 16 + lane16;
            w3v[j] = W3[col];
            bv[j] = bias[col];
        }
        #pragma unroll
        for (int i = 0; i < 4; ++i) {
            #pragma unroll
            for (int r = 0; r < 4; ++r) {
                float s = 0.f;
                #pragma unroll
                for (int j = 0; j < 4; ++j) {
                    float v = fmaxf(acc[i][j][r] + bv[j], 0.f);
                    s += v * w3v[j];
                }
                // reduce across lane16 (stays within the same quad)
                s += __shfl_xor(s, 1, 64);
                s += __shfl_xor(s, 2, 64);
                s += __shfl_xor(s, 4, 64);
                s += __shfl_xor(s, 8, 64);
                if (lane16 == 0) {
                    const long row = row0 + wm + i * 16 + quad * 4 + r;
                    atomicAdd(&outp[row], s);
                }
            }
        }
    }
}

// ---------------------------------------------------------------------------
// Launch
// ---------------------------------------------------------------------------
extern "C" void kernel_launch(void* const* d_in, const int* in_sizes, int n_in,
                              void* d_out, int out_size, void* d_ws,
                              size_t ws_size, hipStream_t stream) {
    const float* h  = (const float*)d_in[0];
    const float* W1 = (const float*)d_in[1];
    const float* b1 = (const float*)d_in[2];
    const float* W2 = (const float*)d_in[3];
    const float* b2 = (const float*)d_in[4];
    const float* W3 = (const float*)d_in[5];
    const float* b3 = (const float*)d_in[6];
    float* out = (float*)d_out;

    const int B = 128, T = 254, D = 768, H = 1024;
    const int M = B * T;        // 32512
    const int K1 = 2 * D;       // 1536
    const int N1 = 2 * H;       // 2048
    const int K2 = N1;          // 2048
    const int N2 = H;           // 1024

    char* ws = (char*)d_ws;
    size_t off = 0;
    auto alloc = [&](size_t bytes) {
        char* p = ws + off;
        off += (bytes + 255) & ~(size_t)255;
        return p;
    };
    unsigned short* X   = (unsigned short*)alloc((size_t)M * K1 * 2);  // 99.9 MB
    unsigned short* H1  = (unsigned short*)alloc((size_t)M * N1 * 2);  // 133.2 MB
    unsigned short* W1T = (unsigned short*)alloc((size_t)N1 * K1 * 2); // 6.3 MB
    unsigned short* W2T = (unsigned short*)alloc((size_t)N2 * K2 * 2); // 4.2 MB

    dim3 tb(32, 8);
    transpose_cast<<<dim3(N1 / 32, K1 / 32), tb, 0, stream>>>(W1, W1T, K1, N1);
    transpose_cast<<<dim3(N2 / 32, K2 / 32), tb, 0, stream>>>(W2, W2T, K2, N2);

    feats_kernel<<<dim3(B, D / 256), 256, 0, stream>>>(h, X, B, T, D);

    init_out<<<dim3((M + 255) / 256), 256, 0, stream>>>(out, b3, M);

    // grid (Ncols, Mrows): fast dim = column blocks -> A panel reuse in cache
    gemm_bt_bias_relu<false><<<dim3(N1 / 128, M / 128), 256, 0, stream>>>(
        X, W1T, b1, H1, nullptr, nullptr, M, N1, K1);
    gemm_bt_bias_relu<true><<<dim3(N2 / 128, M / 128), 256, 0, stream>>>(
        H1, W2T, b2, nullptr, W3, out, M, N2, K2);
}